// Round 1
// baseline (1910.874 us; speedup 1.0000x reference)
//
#include <hip/hip_runtime.h>

typedef __attribute__((ext_vector_type(8))) short bf16x8;
typedef __attribute__((ext_vector_type(4))) float f32x4;

#define SEQ   16
#define NAG   128
#define HDIM  512
#define KHALF 512
#define BM    32

__device__ __forceinline__ unsigned short f2bf(float x) {
  unsigned int u = __float_as_uint(x);
  return (unsigned short)((u + 0x7fffu + ((u >> 16) & 1u)) >> 16);  // RNE
}
__device__ __forceinline__ float sigm(float x) { return 1.0f / (1.0f + __expf(-x)); }
__device__ __forceinline__ float tanh_(float x) { return 2.0f / (1.0f + __expf(-2.0f * x)) - 1.0f; }

// Pack [W_ih | W_hh] -> bf16 Wb[2048][1024], bsum[n] = b_ih[n]+b_hh[n]
__global__ void prep_weights(const float* __restrict__ Wih, const float* __restrict__ Whh,
                             const float* __restrict__ bih, const float* __restrict__ bhh,
                             unsigned short* __restrict__ Wb, float* __restrict__ bsum) {
  int n = blockIdx.x;
  for (int k = threadIdx.x; k < 1024; k += 256) {
    float v = (k < KHALF) ? Wih[(size_t)n * KHALF + k] : Whh[(size_t)n * KHALF + (k - KHALF)];
    Wb[(size_t)n * 1024 + k] = f2bf(v);
  }
  if (threadIdx.x == 0) bsum[n] = bih[n] + bhh[n];
}

template <bool PREP>
__global__ __launch_bounds__(512, 2)
void lstm_fused(const float* __restrict__ hxs, const float* __restrict__ cxs,
                const float* __restrict__ h_self, const float* __restrict__ h_inter,
                const int* __restrict__ reset,
                const unsigned short* __restrict__ Wb, const float* __restrict__ bsum,
                const float* __restrict__ Wih, const float* __restrict__ Whh,
                const float* __restrict__ bih, const float* __restrict__ bhh,
                float* __restrict__ out) {
  // LDS: x tile (bf16) + double-buffered h tile (bf16), XOR-swizzled in k
  __shared__ unsigned short x_lds[BM * KHALF];        // 32 KB
  __shared__ unsigned short h_lds[2][BM * KHALF];     // 64 KB

  const int tid  = threadIdx.x;
  const int wave = tid >> 6;
  const int lane = tid & 63;
  const int col  = lane & 15;      // MFMA col / A-row selector
  const int kgrp = lane >> 4;      // k-group (0..3)

  const int m0     = blockIdx.x * BM;
  const int traj   = m0 >> 7;       // all 32 rows share one trajectory
  const int agent0 = m0 & 127;

  // staging thread mapping: 512 threads -> 32 rows x 16 lanes
  const int rS  = tid >> 4;
  const int l16 = tid & 15;
  const int swS = (rS & 7) << 3;   // element-index swizzle (==byte<<4 for bf16)

  { // stage h0 = hxs[traj*16 + 0] rows
    const float* src = hxs + ((size_t)traj * SEQ * NAG + (agent0 + rS)) * HDIM;
    #pragma unroll
    for (int p = 0; p < 8; ++p) {
      int k = p * 64 + l16 * 4;
      float4 v = *reinterpret_cast<const float4*>(src + k);
      ushort4 u = make_ushort4(f2bf(v.x), f2bf(v.y), f2bf(v.z), f2bf(v.w));
      *reinterpret_cast<ushort4*>(&h_lds[0][rS * KHALF + (k ^ swS)]) = u;
    }
  }

  // persistent per-lane cell state + biases
  float c_reg[2][4][4];   // [row-tile][sub-chunk][reg]
  float biasv[4][4];      // [sub-chunk][quadrant]
  {
    #pragma unroll
    for (int s = 0; s < 4; ++s)
      #pragma unroll
      for (int q = 0; q < 4; ++q) {
        int n = wave * 64 + s * 16 + col + q * KHALF;
        biasv[s][q] = PREP ? bsum[n] : (bih[n] + bhh[n]);
      }
    const size_t cbase = ((size_t)traj * SEQ * NAG + agent0) * HDIM;
    #pragma unroll
    for (int rt = 0; rt < 2; ++rt)
      #pragma unroll
      for (int s = 0; s < 4; ++s)
        #pragma unroll
        for (int j = 0; j < 4; ++j) {
          int row = rt * 16 + (kgrp << 2) + j;
          int hd  = wave * 64 + s * 16 + col;
          c_reg[rt][s][j] = cxs[cbase + (size_t)row * HDIM + hd];
        }
  }

  const size_t CYS = (size_t)SEQ * 64 * NAG * HDIM;  // 67108864

  const int r0 = col, r1 = 16 + col;
  const int sw0 = (r0 & 7) << 3, sw1 = (r1 & 7) << 3;

  for (int t = 0; t < SEQ; ++t) {
    const int cur = t & 1, nxt = cur ^ 1;
    const int b  = traj * SEQ + t;
    const int mt = 1 - reset[b];

    { // stage x_t = [h_self[b][:,256:] | h_inter[b]] -> bf16 LDS
      const float* srcs = h_self  + ((size_t)b * NAG + (agent0 + rS)) * HDIM + 256;
      const float* srci = h_inter + ((size_t)b * NAG + (agent0 + rS)) * 256;
      #pragma unroll
      for (int p = 0; p < 8; ++p) {
        int k = p * 64 + l16 * 4;
        const float* sp = (k < 256) ? (srcs + k) : (srci + (k - 256));
        float4 v = *reinterpret_cast<const float4*>(sp);
        ushort4 u = make_ushort4(f2bf(v.x), f2bf(v.y), f2bf(v.z), f2bf(v.w));
        *reinterpret_cast<ushort4*>(&x_lds[rS * KHALF + (k ^ swS)]) = u;
      }
      if (mt == 0) { // hp = 0 exactly (mask is 0/1)
        ushort4 z = make_ushort4(0, 0, 0, 0);
        #pragma unroll
        for (int p = 0; p < 8; ++p) {
          int k = p * 64 + l16 * 4;
          *reinterpret_cast<ushort4*>(&h_lds[cur][rS * KHALF + (k ^ swS)]) = z;
        }
      }
    }
    __syncthreads();

    #pragma unroll 1
    for (int s = 0; s < 4; ++s) {  // 16 h-dims per sub-chunk, i/f/g/o quadrants together
      const int hd = wave * 64 + s * 16 + col;
      f32x4 acc[2][4];
      #pragma unroll
      for (int rt = 0; rt < 2; ++rt)
        #pragma unroll
        for (int q = 0; q < 4; ++q)
          acc[rt][q] = f32x4{0.f, 0.f, 0.f, 0.f};

      // ---- x half: k in [0,512)
      #pragma unroll 2
      for (int k0 = 0; k0 < KHALF; k0 += 32) {
        const int kk = k0 + kgrp * 8;
        bf16x8 a0 = *reinterpret_cast<const bf16x8*>(&x_lds[r0 * KHALF + (kk ^ sw0)]);
        bf16x8 a1 = *reinterpret_cast<const bf16x8*>(&x_lds[r1 * KHALF + (kk ^ sw1)]);
        #pragma unroll
        for (int q = 0; q < 4; ++q) {
          bf16x8 bq;
          if (PREP) {
            bq = *reinterpret_cast<const bf16x8*>(Wb + (size_t)(hd + q * KHALF) * 1024 + kk);
          } else {
            const float* wr = Wih + (size_t)(hd + q * KHALF) * KHALF + kk;
            float4 w0 = *reinterpret_cast<const float4*>(wr);
            float4 w1 = *reinterpret_cast<const float4*>(wr + 4);
            bq = bf16x8{(short)f2bf(w0.x), (short)f2bf(w0.y), (short)f2bf(w0.z), (short)f2bf(w0.w),
                        (short)f2bf(w1.x), (short)f2bf(w1.y), (short)f2bf(w1.z), (short)f2bf(w1.w)};
          }
          acc[0][q] = __builtin_amdgcn_mfma_f32_16x16x32_bf16(a0, bq, acc[0][q], 0, 0, 0);
          acc[1][q] = __builtin_amdgcn_mfma_f32_16x16x32_bf16(a1, bq, acc[1][q], 0, 0, 0);
        }
      }
      // ---- h half: k in [512,1024)
      #pragma unroll 2
      for (int k0 = 0; k0 < KHALF; k0 += 32) {
        const int kk = k0 + kgrp * 8;
        bf16x8 a0 = *reinterpret_cast<const bf16x8*>(&h_lds[cur][r0 * KHALF + (kk ^ sw0)]);
        bf16x8 a1 = *reinterpret_cast<const bf16x8*>(&h_lds[cur][r1 * KHALF + (kk ^ sw1)]);
        #pragma unroll
        for (int q = 0; q < 4; ++q) {
          bf16x8 bq;
          if (PREP) {
            bq = *reinterpret_cast<const bf16x8*>(Wb + (size_t)(hd + q * KHALF) * 1024 + KHALF + kk);
          } else {
            const float* wr = Whh + (size_t)(hd + q * KHALF) * KHALF + kk;
            float4 w0 = *reinterpret_cast<const float4*>(wr);
            float4 w1 = *reinterpret_cast<const float4*>(wr + 4);
            bq = bf16x8{(short)f2bf(w0.x), (short)f2bf(w0.y), (short)f2bf(w0.z), (short)f2bf(w0.w),
                        (short)f2bf(w1.x), (short)f2bf(w1.y), (short)f2bf(w1.z), (short)f2bf(w1.w)};
          }
          acc[0][q] = __builtin_amdgcn_mfma_f32_16x16x32_bf16(a0, bq, acc[0][q], 0, 0, 0);
          acc[1][q] = __builtin_amdgcn_mfma_f32_16x16x32_bf16(a1, bq, acc[1][q], 0, 0, 0);
        }
      }

      // ---- LSTM cell: fully lane-local (i,f,g,o share (row,hd) per lane-reg)
      #pragma unroll
      for (int rt = 0; rt < 2; ++rt) {
        const int rbase = rt * 16 + (kgrp << 2);
        const size_t obase = ((size_t)b * NAG + (agent0 + rbase)) * HDIM + hd;
        #pragma unroll
        for (int j = 0; j < 4; ++j) {
          float gi = acc[rt][0][j] + biasv[s][0];
          float gf = acc[rt][1][j] + biasv[s][1];
          float gg = acc[rt][2][j] + biasv[s][2];
          float go = acc[rt][3][j] + biasv[s][3];
          float cp = mt ? c_reg[rt][s][j] : 0.0f;
          float cn = sigm(gf) * cp + sigm(gi) * tanh_(gg);
          float hn = sigm(go) * tanh_(cn);
          c_reg[rt][s][j] = cn;
          int row = rbase + j;
          h_lds[nxt][row * KHALF + (hd ^ ((row & 7) << 3))] = f2bf(hn);
          out[obase + (size_t)j * HDIM] = hn;          // hys
          out[CYS + obase + (size_t)j * HDIM] = cn;    // cys
        }
      }
    }
    __syncthreads();
  }
}

extern "C" void kernel_launch(void* const* d_in, const int* in_sizes, int n_in,
                              void* d_out, int out_size, void* d_ws, size_t ws_size,
                              hipStream_t stream) {
  (void)in_sizes; (void)n_in; (void)out_size;
  const float* hxs     = (const float*)d_in[1];
  const float* cxs     = (const float*)d_in[2];
  const float* h_self  = (const float*)d_in[3];
  const float* h_inter = (const float*)d_in[4];
  const int*   reset   = (const int*)d_in[5];
  const float* Wih     = (const float*)d_in[6];
  const float* Whh     = (const float*)d_in[7];
  const float* bih     = (const float*)d_in[8];
  const float* bhh     = (const float*)d_in[9];
  float* out = (float*)d_out;

  const size_t needW = (size_t)2048 * 1024 * sizeof(unsigned short);  // 4 MB
  const size_t need  = needW + 2048 * sizeof(float);

  if (d_ws != nullptr && ws_size >= need) {
    unsigned short* Wb = (unsigned short*)d_ws;
    float* bsum = (float*)((char*)d_ws + needW);
    prep_weights<<<2048, 256, 0, stream>>>(Wih, Whh, bih, bhh, Wb, bsum);
    lstm_fused<true><<<256, 512, 0, stream>>>(hxs, cxs, h_self, h_inter, reset,
                                              Wb, bsum, Wih, Whh, bih, bhh, out);
  } else {
    lstm_fused<false><<<256, 512, 0, stream>>>(hxs, cxs, h_self, h_inter, reset,
                                               nullptr, nullptr, Wih, Whh, bih, bhh, out);
  }
}

// Round 2
// 998.428 us; speedup vs baseline: 1.9139x; 1.9139x over previous
//
#include <hip/hip_runtime.h>

typedef __attribute__((ext_vector_type(8))) short bf16x8;
typedef __attribute__((ext_vector_type(16))) float f32x16;

#define SEQ  16
#define NAG  128
#define HD   512

__device__ __forceinline__ unsigned short f2bf(float x) {
  unsigned int u = __float_as_uint(x);
  return (unsigned short)((u + 0x7fffu + ((u >> 16) & 1u)) >> 16);  // RNE
}
__device__ __forceinline__ float sigm(float x) { return 1.0f / (1.0f + __expf(-x)); }
__device__ __forceinline__ float tanh_(float x) { return 2.0f / (1.0f + __expf(-2.0f * x)) - 1.0f; }

// Pack weights into MFMA-fragment order: Wpk[((tile*64 + ks)*64 + lane)*8 + e]
//   tile in [0,64): gate-col tile of 32;  ks in [0,64): k-step of 16
//   lane's fragment: col = tile*32 + (lane&31), k = ks*16 + (lane>>5)*8 + e
// k < 512 -> W_ih[:, k], else W_hh[:, k-512].  Also bsum[n] = b_ih[n]+b_hh[n].
__global__ void prep_pack(const float* __restrict__ Wih, const float* __restrict__ Whh,
                          const float* __restrict__ bih, const float* __restrict__ bhh,
                          unsigned short* __restrict__ Wpk, float* __restrict__ bsum) {
  const int t  = blockIdx.x >> 6;
  const int ks = blockIdx.x & 63;
  const int l  = threadIdx.x;
  const int n  = t * 32 + (l & 31);
  const int k  = ks * 16 + (l >> 5) * 8;
  const float* p = (k < 512) ? (Wih + (size_t)n * 512 + k) : (Whh + (size_t)n * 512 + (k - 512));
  float4 w0 = *reinterpret_cast<const float4*>(p);
  float4 w1 = *reinterpret_cast<const float4*>(p + 4);
  bf16x8 v = {(short)f2bf(w0.x), (short)f2bf(w0.y), (short)f2bf(w0.z), (short)f2bf(w0.w),
              (short)f2bf(w1.x), (short)f2bf(w1.y), (short)f2bf(w1.z), (short)f2bf(w1.w)};
  *reinterpret_cast<bf16x8*>(Wpk + ((size_t)blockIdx.x * 64 + l) * 8) = v;
  if (ks == 0 && l < 32) bsum[n] = bih[n] + bhh[n];
}

template <bool PACKED>
__device__ __forceinline__ bf16x8 loadB(const unsigned short* __restrict__ Wpk,
                                        const float* __restrict__ Wih,
                                        const float* __restrict__ Whh,
                                        int tile, int ks, int lane) {
  if (PACKED) {
    return *reinterpret_cast<const bf16x8*>(Wpk + (((size_t)tile * 64 + ks) * 64 + lane) * 8);
  } else {
    int n = tile * 32 + (lane & 31);
    int k = ks * 16 + (lane >> 5) * 8;
    const float* p = (k < 512) ? (Wih + (size_t)n * 512 + k) : (Whh + (size_t)n * 512 + (k - 512));
    float4 w0 = *reinterpret_cast<const float4*>(p);
    float4 w1 = *reinterpret_cast<const float4*>(p + 4);
    return bf16x8{(short)f2bf(w0.x), (short)f2bf(w0.y), (short)f2bf(w0.z), (short)f2bf(w0.w),
                  (short)f2bf(w1.x), (short)f2bf(w1.y), (short)f2bf(w1.z), (short)f2bf(w1.w)};
  }
}

template <bool PACKED>
__global__ __launch_bounds__(512, 2)
void lstm32(const float* __restrict__ hxs, const float* __restrict__ cxs,
            const float* __restrict__ h_self, const float* __restrict__ h_inter,
            const int* __restrict__ reset,
            const unsigned short* __restrict__ Wpk, const float* __restrict__ bsum,
            const float* __restrict__ Wih, const float* __restrict__ Whh,
            const float* __restrict__ bih, const float* __restrict__ bhh,
            float* __restrict__ out) {
  __shared__ __align__(16) unsigned short x_lds[32 * 512];      // 32 KB
  __shared__ __align__(16) unsigned short h_lds[2][32 * 512];   // 64 KB

  const int tid  = threadIdx.x;
  const int w    = tid >> 6;
  const int lane = tid & 63;
  const int colB = lane & 31;     // B col within tile / C-D col
  const int khB  = lane >> 5;     // k-half selector
  const int row  = colB;          // A row = lane&31
  const int asw  = (row & 7) << 3;

  const int bid    = blockIdx.x;
  const int traj   = bid >> 2;
  const int agent0 = (bid & 3) * 32;

  // staging mapping: 512 threads -> 32 rows x 16 lane16
  const int rS  = tid >> 4;
  const int l16 = tid & 15;
  const int swS = (rS & 7) << 3;

  const size_t CYS = (size_t)SEQ * 64 * NAG * HD;  // 67108864

  { // stage h(0) = hxs[traj*SEQ] rows (mask applied in-loop via zeroing)
    const float* src = hxs + ((size_t)traj * SEQ * NAG + (agent0 + rS)) * HD;
    #pragma unroll
    for (int p = 0; p < 8; ++p) {
      int k = p * 64 + l16 * 4;
      float4 v = *reinterpret_cast<const float4*>(src + k);
      ushort4 u4 = make_ushort4(f2bf(v.x), f2bf(v.y), f2bf(v.z), f2bf(v.w));
      *reinterpret_cast<ushort4*>(&h_lds[0][rS * 512 + (k ^ swS)]) = u4;
    }
  }

  // persistent per-lane state
  float c_reg[2][16];
  float biasv[2][4];
  {
    #pragma unroll
    for (int u = 0; u < 2; ++u)
      #pragma unroll
      for (int q = 0; q < 4; ++q) {
        int n = q * 512 + w * 64 + u * 32 + colB;
        biasv[u][q] = PACKED ? bsum[n] : (bih[n] + bhh[n]);
      }
    const size_t cbase = ((size_t)traj * SEQ * NAG + agent0) * HD;
    #pragma unroll
    for (int u = 0; u < 2; ++u)
      #pragma unroll
      for (int reg = 0; reg < 16; ++reg) {
        int r  = (reg & 3) + 8 * (reg >> 2) + 4 * khB;
        int hd = w * 64 + u * 32 + colB;
        c_reg[u][reg] = cxs[cbase + (size_t)r * HD + hd];
      }
  }

  for (int t = 0; t < SEQ; ++t) {
    const int b  = traj * SEQ + t;
    const int mt = 1 - reset[b];
    const unsigned short* hcur = h_lds[t & 1];
    unsigned short*       hnxt = h_lds[(t & 1) ^ 1];

    { // stage x(t) = [h_self[b][:,256:] | h_inter[b]] -> bf16
      const float* srcs = h_self  + ((size_t)b * NAG + (agent0 + rS)) * HD + 256;
      const float* srci = h_inter + ((size_t)b * NAG + (agent0 + rS)) * 256;
      #pragma unroll
      for (int p = 0; p < 8; ++p) {
        int k = p * 64 + l16 * 4;
        const float* sp = (k < 256) ? (srcs + k) : (srci + (k - 256));
        float4 v = *reinterpret_cast<const float4*>(sp);
        ushort4 u4 = make_ushort4(f2bf(v.x), f2bf(v.y), f2bf(v.z), f2bf(v.w));
        *reinterpret_cast<ushort4*>(&x_lds[rS * 512 + (k ^ swS)]) = u4;
      }
      if (mt == 0) {  // h input of this step is exactly zero
        uint4* pz = (uint4*)h_lds[t & 1];
        #pragma unroll
        for (int i = 0; i < 4; ++i) pz[tid + i * 512] = uint4{0, 0, 0, 0};
      }
    }
    __syncthreads();

    auto lda = [&](int ks) -> bf16x8 {
      int kk = (ks & 31) * 16 + khB * 8;
      const unsigned short* src = (ks < 32) ? x_lds : hcur;
      return *reinterpret_cast<const bf16x8*>(src + row * 512 + (kk ^ asw));
    };

    #pragma unroll
    for (int u = 0; u < 2; ++u) {
      const int t0 = 0 * 16 + w * 2 + u, t1 = 1 * 16 + w * 2 + u,
                t2 = 2 * 16 + w * 2 + u, t3 = 3 * 16 + w * 2 + u;
      f32x16 acc[4];
      #pragma unroll
      for (int q = 0; q < 4; ++q)
        #pragma unroll
        for (int e = 0; e < 16; ++e) acc[q][e] = 0.0f;

      bf16x8 Ba[4], Bb[4];
      Ba[0] = loadB<PACKED>(Wpk, Wih, Whh, t0, 0, lane);
      Ba[1] = loadB<PACKED>(Wpk, Wih, Whh, t1, 0, lane);
      Ba[2] = loadB<PACKED>(Wpk, Wih, Whh, t2, 0, lane);
      Ba[3] = loadB<PACKED>(Wpk, Wih, Whh, t3, 0, lane);
      Bb[0] = loadB<PACKED>(Wpk, Wih, Whh, t0, 1, lane);
      Bb[1] = loadB<PACKED>(Wpk, Wih, Whh, t1, 1, lane);
      Bb[2] = loadB<PACKED>(Wpk, Wih, Whh, t2, 1, lane);
      Bb[3] = loadB<PACKED>(Wpk, Wih, Whh, t3, 1, lane);

      #pragma unroll 1
      for (int kp = 0; kp < 32; ++kp) {
        const int ks0 = kp * 2;
        bf16x8 a0 = lda(ks0);
        __builtin_amdgcn_s_setprio(1);
        acc[0] = __builtin_amdgcn_mfma_f32_32x32x16_bf16(a0, Ba[0], acc[0], 0, 0, 0);
        acc[1] = __builtin_amdgcn_mfma_f32_32x32x16_bf16(a0, Ba[1], acc[1], 0, 0, 0);
        acc[2] = __builtin_amdgcn_mfma_f32_32x32x16_bf16(a0, Ba[2], acc[2], 0, 0, 0);
        acc[3] = __builtin_amdgcn_mfma_f32_32x32x16_bf16(a0, Ba[3], acc[3], 0, 0, 0);
        __builtin_amdgcn_s_setprio(0);
        const int ksn0 = (ks0 + 2 < 64) ? ks0 + 2 : 63;
        Ba[0] = loadB<PACKED>(Wpk, Wih, Whh, t0, ksn0, lane);
        Ba[1] = loadB<PACKED>(Wpk, Wih, Whh, t1, ksn0, lane);
        Ba[2] = loadB<PACKED>(Wpk, Wih, Whh, t2, ksn0, lane);
        Ba[3] = loadB<PACKED>(Wpk, Wih, Whh, t3, ksn0, lane);
        bf16x8 a1 = lda(ks0 + 1);
        __builtin_amdgcn_s_setprio(1);
        acc[0] = __builtin_amdgcn_mfma_f32_32x32x16_bf16(a1, Bb[0], acc[0], 0, 0, 0);
        acc[1] = __builtin_amdgcn_mfma_f32_32x32x16_bf16(a1, Bb[1], acc[1], 0, 0, 0);
        acc[2] = __builtin_amdgcn_mfma_f32_32x32x16_bf16(a1, Bb[2], acc[2], 0, 0, 0);
        acc[3] = __builtin_amdgcn_mfma_f32_32x32x16_bf16(a1, Bb[3], acc[3], 0, 0, 0);
        __builtin_amdgcn_s_setprio(0);
        const int ksn1 = (ks0 + 3 < 64) ? ks0 + 3 : 63;
        Bb[0] = loadB<PACKED>(Wpk, Wih, Whh, t0, ksn1, lane);
        Bb[1] = loadB<PACKED>(Wpk, Wih, Whh, t1, ksn1, lane);
        Bb[2] = loadB<PACKED>(Wpk, Wih, Whh, t2, ksn1, lane);
        Bb[3] = loadB<PACKED>(Wpk, Wih, Whh, t3, ksn1, lane);
      }

      // LSTM cell for this u-half: lane-local i/f/g/o at same (row, hd)
      const int hd = w * 64 + u * 32 + colB;
      #pragma unroll
      for (int reg = 0; reg < 16; ++reg) {
        float gi = acc[0][reg] + biasv[u][0];
        float gf = acc[1][reg] + biasv[u][1];
        float gg = acc[2][reg] + biasv[u][2];
        float go = acc[3][reg] + biasv[u][3];
        float cp = mt ? c_reg[u][reg] : 0.0f;
        float cn = sigm(gf) * cp + sigm(gi) * tanh_(gg);
        float hn = sigm(go) * tanh_(cn);
        c_reg[u][reg] = cn;
        int r = (reg & 3) + 8 * (reg >> 2) + 4 * khB;
        size_t ob = ((size_t)b * NAG + agent0 + r) * HD + hd;
        out[ob] = hn;
        out[CYS + ob] = cn;
        hnxt[r * 512 + (hd ^ ((r & 7) << 3))] = f2bf(hn);
      }
    }
    __syncthreads();
  }
}

extern "C" void kernel_launch(void* const* d_in, const int* in_sizes, int n_in,
                              void* d_out, int out_size, void* d_ws, size_t ws_size,
                              hipStream_t stream) {
  (void)in_sizes; (void)n_in; (void)out_size;
  const float* hxs     = (const float*)d_in[1];
  const float* cxs     = (const float*)d_in[2];
  const float* h_self  = (const float*)d_in[3];
  const float* h_inter = (const float*)d_in[4];
  const int*   reset   = (const int*)d_in[5];
  const float* Wih     = (const float*)d_in[6];
  const float* Whh     = (const float*)d_in[7];
  const float* bih     = (const float*)d_in[8];
  const float* bhh     = (const float*)d_in[9];
  float* out = (float*)d_out;

  const size_t needW = (size_t)2048 * 1024 * sizeof(unsigned short);  // 4 MB
  const size_t need  = needW + 2048 * sizeof(float);

  if (d_ws != nullptr && ws_size >= need) {
    unsigned short* Wpk = (unsigned short*)d_ws;
    float* bsum = (float*)((char*)d_ws + needW);
    prep_pack<<<4096, 64, 0, stream>>>(Wih, Whh, bih, bhh, Wpk, bsum);
    lstm32<true><<<256, 512, 0, stream>>>(hxs, cxs, h_self, h_inter, reset,
                                          Wpk, bsum, Wih, Whh, bih, bhh, out);
  } else {
    lstm32<false><<<256, 512, 0, stream>>>(hxs, cxs, h_self, h_inter, reset,
                                           nullptr, nullptr, Wih, Whh, bih, bhh, out);
  }
}